// Round 1
// baseline (1039.351 us; speedup 1.0000x reference)
//
#include <hip/hip_runtime.h>

#define BB 8
#define NN 1024
#define KK 20
#define EPSV 1e-5f

__device__ __forceinline__ unsigned fenc(float f) {
  unsigned u = __float_as_uint(f);
  return (u & 0x80000000u) ? ~u : (u | 0x80000000u);
}
__device__ __forceinline__ float fdec(unsigned u) {
  u = (u & 0x80000000u) ? (u & 0x7FFFFFFFu) : ~u;
  return __uint_as_float(u);
}

// ---- per-point squared norm: xx[b*N+n] = sum_c x[b][c][n]^2
template<int C>
__global__ __launch_bounds__(256) void xx_kernel(const float* __restrict__ x, float* __restrict__ xx) {
  int p = blockIdx.x * 256 + threadIdx.x;
  if (p >= BB * NN) return;
  int b = p >> 10, n = p & (NN - 1);
  const float* xb = x + (size_t)b * C * NN + n;
  float s = 0.f;
  #pragma unroll
  for (int c = 0; c < C; ++c) { float t = xb[(size_t)c * NN]; s = fmaf(t, t, s); }
  xx[p] = s;
}

// ---- pairwise d[i][j] = 2<xi,xj> - xx_i - xx_j  (64x64 tiles; batches b0..b0+nb-1, d indexed by local z)
template<int C>
__global__ __launch_bounds__(256) void dist_kernel(const float* __restrict__ x, const float* __restrict__ xx,
                                                   float* __restrict__ d, int b0) {
  constexpr int CC = (C < 64) ? C : 64;
  __shared__ __align__(16) float xi[CC][64];
  __shared__ __align__(16) float xj[CC][64];
  int bl = blockIdx.z, b = b0 + bl;
  int i0 = blockIdx.y * 64, j0 = blockIdx.x * 64;
  int t = threadIdx.x;
  int tj = t & 15, ti = t >> 4;
  float acc[4][4] = {};
  const float* xb = x + (size_t)b * C * NN;
  for (int c0 = 0; c0 < C; c0 += CC) {
    __syncthreads();
    for (int p = t; p < CC * 64; p += 256) {
      int cc = p >> 6, col = p & 63;
      xi[cc][col] = xb[(size_t)(c0 + cc) * NN + i0 + col];
      xj[cc][col] = xb[(size_t)(c0 + cc) * NN + j0 + col];
    }
    __syncthreads();
    #pragma unroll
    for (int cc = 0; cc < CC; ++cc) {
      float4 A  = *reinterpret_cast<const float4*>(&xi[cc][ti * 4]);
      float4 Bv = *reinterpret_cast<const float4*>(&xj[cc][tj * 4]);
      float av[4] = {A.x, A.y, A.z, A.w};
      float bv[4] = {Bv.x, Bv.y, Bv.z, Bv.w};
      #pragma unroll
      for (int a = 0; a < 4; ++a)
        #pragma unroll
        for (int q = 0; q < 4; ++q)
          acc[a][q] = fmaf(av[a], bv[q], acc[a][q]);
    }
  }
  #pragma unroll
  for (int a = 0; a < 4; ++a) {
    int i = i0 + ti * 4 + a;
    float xxi = xx[b * NN + i];
    float4 o;
    o.x = 2.f * acc[a][0] - xxi - xx[b * NN + j0 + tj * 4 + 0];
    o.y = 2.f * acc[a][1] - xxi - xx[b * NN + j0 + tj * 4 + 1];
    o.z = 2.f * acc[a][2] - xxi - xx[b * NN + j0 + tj * 4 + 2];
    o.w = 2.f * acc[a][3] - xxi - xx[b * NN + j0 + tj * 4 + 3];
    *reinterpret_cast<float4*>(&d[((size_t)bl * NN + i) * NN + j0 + tj * 4]) = o;
  }
}

// ---- top-20 extraction per row (lower-index tie-break, matches lax.top_k set)
__global__ __launch_bounds__(256) void topk_kernel(const float* __restrict__ d, int* __restrict__ idx, int b0) {
  __shared__ float sd[NN];
  __shared__ float swv[4];
  __shared__ int   swi[4];
  int bl = blockIdx.y, b = b0 + bl, i = blockIdx.x;
  const float* row = d + ((size_t)bl * NN + i) * NN;
  int t = threadIdx.x;
  for (int j = t; j < NN; j += 256) sd[j] = row[j];
  __syncthreads();
  int lane = t & 63, w = t >> 6;
  int* op = idx + ((size_t)b * NN + i) * KK;
  for (int r = 0; r < KK; ++r) {
    float bv = -3.4e38f; int bi = NN;
    for (int j = t; j < NN; j += 256) {
      float v = sd[j];
      if (v > bv) { bv = v; bi = j; }  // ascending j: keeps smallest index on tie
    }
    #pragma unroll
    for (int s = 1; s < 64; s <<= 1) {
      float ov = __shfl_xor(bv, s);
      int   oi = __shfl_xor(bi, s);
      if (ov > bv || (ov == bv && oi < bi)) { bv = ov; bi = oi; }
    }
    if (lane == 0) { swv[w] = bv; swi[w] = bi; }
    __syncthreads();
    if (t == 0) {
      float fv = swv[0]; int fi = swi[0];
      for (int w2 = 1; w2 < 4; ++w2)
        if (swv[w2] > fv || (swv[w2] == fv && swi[w2] < fi)) { fv = swv[w2]; fi = swi[w2]; }
      op[r] = fi;
      sd[fi] = -3.4e38f;
    }
    __syncthreads();
  }
}

// ---- P_lo[b][o][n] = sum_{c<C} W[o][c] x[b][c][n];  P_hi uses W[o][C+c]
template<int C, int O>
__global__ __launch_bounds__(256) void pgemm_kernel(const float* __restrict__ x, const float* __restrict__ W,
                                                    float* __restrict__ Plo, float* __restrict__ Phi) {
  constexpr int CC = (C < 64) ? C : 64;
  __shared__ __align__(16) float xs[CC][64];
  __shared__ __align__(16) float wls[CC][68];
  __shared__ __align__(16) float whs[CC][68];
  int b = blockIdx.z;
  int o0 = blockIdx.y * 64, n0 = blockIdx.x * 64;
  int t = threadIdx.x;
  int tn = t & 15, to = t >> 4;
  float accl[4][4] = {}, acch[4][4] = {};
  const float* xb = x + (size_t)b * C * NN;
  for (int c0 = 0; c0 < C; c0 += CC) {
    __syncthreads();
    for (int p = t; p < CC * 64; p += 256) {
      int cc = p >> 6, col = p & 63;
      xs[cc][col] = xb[(size_t)(c0 + cc) * NN + n0 + col];
    }
    for (int p = t; p < 64 * CC; p += 256) {
      int ol = p / CC, cc = p % CC;
      wls[cc][ol] = W[(size_t)(o0 + ol) * (2 * C) + c0 + cc];
      whs[cc][ol] = W[(size_t)(o0 + ol) * (2 * C) + C + c0 + cc];
    }
    __syncthreads();
    #pragma unroll
    for (int cc = 0; cc < CC; ++cc) {
      float4 X  = *reinterpret_cast<const float4*>(&xs[cc][tn * 4]);
      float4 Wl = *reinterpret_cast<const float4*>(&wls[cc][to * 4]);
      float4 Wh = *reinterpret_cast<const float4*>(&whs[cc][to * 4]);
      float xv[4] = {X.x, X.y, X.z, X.w};
      float wl[4] = {Wl.x, Wl.y, Wl.z, Wl.w};
      float wh[4] = {Wh.x, Wh.y, Wh.z, Wh.w};
      #pragma unroll
      for (int a = 0; a < 4; ++a)
        #pragma unroll
        for (int q = 0; q < 4; ++q) {
          accl[a][q] = fmaf(wl[a], xv[q], accl[a][q]);
          acch[a][q] = fmaf(wh[a], xv[q], acch[a][q]);
        }
    }
  }
  #pragma unroll
  for (int a = 0; a < 4; ++a) {
    int o = o0 + to * 4 + a;
    size_t base = ((size_t)b * O + o) * NN + n0 + tn * 4;
    float4 vl = {accl[a][0], accl[a][1], accl[a][2], accl[a][3]};
    float4 vh = {acch[a][0], acch[a][1], acch[a][2], acch[a][3]};
    *reinterpret_cast<float4*>(&Plo[base]) = vl;
    *reinterpret_cast<float4*>(&Phi[base]) = vh;
  }
}

// ---- z = max_k Plo[o][idx[n][k]] - Plo[o][n] + Phi[o][n]; out = relu(bn(z))
__global__ __launch_bounds__(256) void edgemax_kernel(const float* __restrict__ Plo, const float* __restrict__ Phi,
    const int* __restrict__ idx, const float* __restrict__ g, const float* __restrict__ bt,
    const float* __restrict__ m, const float* __restrict__ v,
    float* __restrict__ xout, int O) {
  int b = blockIdx.z, o = blockIdx.y;
  int n = blockIdx.x * 256 + threadIdx.x;
  const float* pl = Plo + ((size_t)b * O + o) * NN;
  const int* ip = idx + ((size_t)b * NN + n) * KK;
  float mx = -3.4e38f;
  #pragma unroll
  for (int k = 0; k < KK; ++k) mx = fmaxf(mx, pl[ip[k]]);
  float z = mx - pl[n] + Phi[((size_t)b * O + o) * NN + n];
  float inv = g[o] / sqrtf(v[o] + EPSV);
  float y = fmaf(z, inv, bt[o] - m[o] * inv);
  xout[((size_t)b * O + o) * NN + n] = fmaxf(y, 0.f);
}

// ---- conv5 (512->1024) fused with global max over n via encoded atomicMax
__global__ __launch_bounds__(256) void conv5_kernel(const float* __restrict__ x1, const float* __restrict__ x2,
    const float* __restrict__ x3, const float* __restrict__ x4, const float* __restrict__ W5,
    unsigned* __restrict__ henc) {
  __shared__ __align__(16) float xs[32][64];
  __shared__ __align__(16) float ws[32 * 264];
  int b = blockIdx.z;
  int o0 = blockIdx.y * 256, n0 = blockIdx.x * 64;
  int t = threadIdx.x;
  int to = t & 63, ng = t >> 6;
  float acc[4][16] = {};
  for (int c0 = 0; c0 < 512; c0 += 32) {
    __syncthreads();
    const float* srcbase; int cbase;
    if (c0 < 64)       { srcbase = x1 + (size_t)b * 64  * NN; cbase = c0; }
    else if (c0 < 128) { srcbase = x2 + (size_t)b * 64  * NN; cbase = c0 - 64; }
    else if (c0 < 256) { srcbase = x3 + (size_t)b * 128 * NN; cbase = c0 - 128; }
    else               { srcbase = x4 + (size_t)b * 256 * NN; cbase = c0 - 256; }
    for (int p = t; p < 32 * 64; p += 256) {
      int cc = p >> 6, nn2 = p & 63;
      xs[cc][nn2] = srcbase[(size_t)(cbase + cc) * NN + n0 + nn2];
    }
    for (int p = t; p < 256 * 32; p += 256) {
      int ol = p >> 5, cc = p & 31;
      ws[cc * 264 + ol] = W5[(size_t)(o0 + ol) * 512 + c0 + cc];
    }
    __syncthreads();
    #pragma unroll
    for (int cc = 0; cc < 32; ++cc) {
      float4 w = *reinterpret_cast<const float4*>(&ws[cc * 264 + to * 4]);
      #pragma unroll
      for (int j = 0; j < 16; ++j) {
        float xv = xs[cc][ng * 16 + j];
        acc[0][j] = fmaf(w.x, xv, acc[0][j]);
        acc[1][j] = fmaf(w.y, xv, acc[1][j]);
        acc[2][j] = fmaf(w.z, xv, acc[2][j]);
        acc[3][j] = fmaf(w.w, xv, acc[3][j]);
      }
    }
  }
  #pragma unroll
  for (int a = 0; a < 4; ++a) {
    float mx = acc[a][0];
    #pragma unroll
    for (int j = 1; j < 16; ++j) mx = fmaxf(mx, acc[a][j]);
    atomicMax(&henc[b * 1024 + o0 + to * 4 + a], fenc(mx));
  }
}

// ---- decode max, bn5+relu, then 3 FC layers; one block per batch element
__global__ __launch_bounds__(256) void fc_kernel(
    const unsigned* __restrict__ henc,
    const float* __restrict__ g5, const float* __restrict__ b5, const float* __restrict__ m5, const float* __restrict__ v5,
    const float* __restrict__ L1W,
    const float* __restrict__ g6, const float* __restrict__ b6, const float* __restrict__ m6, const float* __restrict__ v6,
    const float* __restrict__ L2W, const float* __restrict__ L2b,
    const float* __restrict__ g7, const float* __restrict__ b7, const float* __restrict__ m7, const float* __restrict__ v7,
    const float* __restrict__ L3W, const float* __restrict__ L3b,
    float* __restrict__ out) {
  __shared__ float sh[1024];
  __shared__ float sy1[512];
  __shared__ float sy2[256];
  int b = blockIdx.x, t = threadIdx.x;
  for (int o = t; o < 1024; o += 256) {
    float f = fdec(henc[b * 1024 + o]);
    float inv = g5[o] / sqrtf(v5[o] + EPSV);
    sh[o] = fmaxf(fmaf(f, inv, b5[o] - m5[o] * inv), 0.f);
  }
  __syncthreads();
  for (int o = t; o < 512; o += 256) {
    float acc = 0.f;
    const float4* w4 = reinterpret_cast<const float4*>(L1W + (size_t)o * 1024);
    const float4* h4 = reinterpret_cast<const float4*>(sh);
    for (int c = 0; c < 256; ++c) {
      float4 a = w4[c], q = h4[c];
      acc += a.x * q.x + a.y * q.y + a.z * q.z + a.w * q.w;
    }
    float inv = g6[o] / sqrtf(v6[o] + EPSV);
    sy1[o] = fmaxf(fmaf(acc, inv, b6[o] - m6[o] * inv), 0.f);
  }
  __syncthreads();
  {
    int o = t;
    float acc = L2b[o];
    const float4* w4 = reinterpret_cast<const float4*>(L2W + (size_t)o * 512);
    const float4* y4 = reinterpret_cast<const float4*>(sy1);
    for (int c = 0; c < 128; ++c) {
      float4 a = w4[c], q = y4[c];
      acc += a.x * q.x + a.y * q.y + a.z * q.z + a.w * q.w;
    }
    float inv = g7[o] / sqrtf(v7[o] + EPSV);
    sy2[o] = fmaxf(fmaf(acc, inv, b7[o] - m7[o] * inv), 0.f);
  }
  __syncthreads();
  if (t < 8) {
    float acc = L3b[t];
    const float4* w4 = reinterpret_cast<const float4*>(L3W + (size_t)t * 256);
    const float4* y4 = reinterpret_cast<const float4*>(sy2);
    for (int c = 0; c < 64; ++c) {
      float4 a = w4[c], q = y4[c];
      acc += a.x * q.x + a.y * q.y + a.z * q.z + a.w * q.w;
    }
    out[b * 8 + t] = acc;
  }
}

extern "C" void kernel_launch(void* const* d_in, const int* in_sizes, int n_in,
                              void* d_out, int out_size, void* d_ws, size_t ws_size,
                              hipStream_t stream) {
  (void)in_sizes; (void)n_in; (void)out_size;
  const float* x   = (const float*)d_in[0];
  const float* W1  = (const float*)d_in[1];
  const float* W2  = (const float*)d_in[2];
  const float* W3  = (const float*)d_in[3];
  const float* W4  = (const float*)d_in[4];
  const float* W5  = (const float*)d_in[5];
  const float* bnp[7][4];
  for (int i = 0; i < 7; ++i)
    for (int j = 0; j < 4; ++j)
      bnp[i][j] = (const float*)d_in[6 + i * 4 + j];
  const float* L1W = (const float*)d_in[34];
  const float* L2W = (const float*)d_in[35];
  const float* L2b = (const float*)d_in[36];
  const float* L3W = (const float*)d_in[37];
  const float* L3b = (const float*)d_in[38];
  float* out = (float*)d_out;

  char* wsb = (char*)d_ws;
  size_t off = 0;
  auto alloc = [&](size_t bytes) -> void* {
    void* p = wsb + off; off += (bytes + 255) & ~(size_t)255; return p;
  };
  int*      idx  = (int*)     alloc((size_t)BB * NN * KK * 4);
  float*    xx   = (float*)   alloc((size_t)BB * NN * 4);
  float*    x1   = (float*)   alloc((size_t)BB * 64  * NN * 4);
  float*    x2   = (float*)   alloc((size_t)BB * 64  * NN * 4);
  float*    x3   = (float*)   alloc((size_t)BB * 128 * NN * 4);
  float*    x4   = (float*)   alloc((size_t)BB * 256 * NN * 4);
  float*    Plo  = (float*)   alloc((size_t)BB * 256 * NN * 4);
  float*    Phi  = (float*)   alloc((size_t)BB * 256 * NN * 4);
  unsigned* henc = (unsigned*)alloc((size_t)BB * 1024 * 4);
  // distance buffer takes whatever is left; process batches in chunks of nb
  size_t left = (ws_size > off) ? (ws_size - off) : 0;
  int nb = 8;
  while (nb > 1 && (size_t)nb * NN * NN * 4 > left) nb >>= 1;
  float* dbuf = (float*)(wsb + off);

  dim3 thr(256);
  #define KNN_PHASE(CIN, XIN)                                                              \
    xx_kernel<CIN><<<dim3(32), thr, 0, stream>>>(XIN, xx);                                 \
    for (int b0 = 0; b0 < BB; b0 += nb) {                                                  \
      dist_kernel<CIN><<<dim3(16, 16, nb), thr, 0, stream>>>(XIN, xx, dbuf, b0);           \
      topk_kernel<<<dim3(NN, nb), thr, 0, stream>>>(dbuf, idx, b0);                        \
    }

  // ---- level 1: x (C=4) -> x1 (O=64)
  KNN_PHASE(4, x)
  pgemm_kernel<4, 64><<<dim3(16, 1, BB), thr, 0, stream>>>(x, W1, Plo, Phi);
  edgemax_kernel<<<dim3(4, 64, BB), thr, 0, stream>>>(Plo, Phi, idx,
      bnp[0][0], bnp[0][1], bnp[0][2], bnp[0][3], x1, 64);
  // ---- level 2: x1 (C=64) -> x2 (O=64)
  KNN_PHASE(64, x1)
  pgemm_kernel<64, 64><<<dim3(16, 1, BB), thr, 0, stream>>>(x1, W2, Plo, Phi);
  edgemax_kernel<<<dim3(4, 64, BB), thr, 0, stream>>>(Plo, Phi, idx,
      bnp[1][0], bnp[1][1], bnp[1][2], bnp[1][3], x2, 64);
  // ---- level 3: x2 (C=64) -> x3 (O=128)
  KNN_PHASE(64, x2)
  pgemm_kernel<64, 128><<<dim3(16, 2, BB), thr, 0, stream>>>(x2, W3, Plo, Phi);
  edgemax_kernel<<<dim3(4, 128, BB), thr, 0, stream>>>(Plo, Phi, idx,
      bnp[2][0], bnp[2][1], bnp[2][2], bnp[2][3], x3, 128);
  // ---- level 4: x3 (C=128) -> x4 (O=256)
  KNN_PHASE(128, x3)
  pgemm_kernel<128, 256><<<dim3(16, 4, BB), thr, 0, stream>>>(x3, W4, Plo, Phi);
  edgemax_kernel<<<dim3(4, 256, BB), thr, 0, stream>>>(Plo, Phi, idx,
      bnp[3][0], bnp[3][1], bnp[3][2], bnp[3][3], x4, 256);
  #undef KNN_PHASE

  // ---- conv5 + global max-pool
  hipMemsetAsync(henc, 0, (size_t)BB * 1024 * 4, stream);
  conv5_kernel<<<dim3(16, 4, BB), thr, 0, stream>>>(x1, x2, x3, x4, W5, henc);

  // ---- fused FC head
  fc_kernel<<<dim3(BB), thr, 0, stream>>>(henc,
      bnp[4][0], bnp[4][1], bnp[4][2], bnp[4][3], L1W,
      bnp[5][0], bnp[5][1], bnp[5][2], bnp[5][3], L2W, L2b,
      bnp[6][0], bnp[6][1], bnp[6][2], bnp[6][3], L3W, L3b, out);
}

// Round 2
// 907.603 us; speedup vs baseline: 1.1452x; 1.1452x over previous
//
#include <hip/hip_runtime.h>

#define BB 8
#define NN 1024
#define KK 20
#define EPSV 1e-5f

__device__ __forceinline__ unsigned fenc(float f) {
  unsigned u = __float_as_uint(f);
  return (u & 0x80000000u) ? ~u : (u | 0x80000000u);
}
__device__ __forceinline__ float fdec(unsigned u) {
  u = (u & 0x80000000u) ? (u & 0x7FFFFFFFu) : ~u;
  return __uint_as_float(u);
}

// ---- per-point squared norm: xx[b*N+n] = sum_c x[b][c][n]^2
template<int C>
__global__ __launch_bounds__(256) void xx_kernel(const float* __restrict__ x, float* __restrict__ xx) {
  int p = blockIdx.x * 256 + threadIdx.x;
  if (p >= BB * NN) return;
  int b = p >> 10, n = p & (NN - 1);
  const float* xb = x + (size_t)b * C * NN + n;
  float s = 0.f;
  #pragma unroll
  for (int c = 0; c < C; ++c) { float t = xb[(size_t)c * NN]; s = fmaf(t, t, s); }
  xx[p] = s;
}

// ---- pairwise d[i][j] = 2<xi,xj> - xx_i - xx_j  (64x64 tiles; batches b0..b0+nb-1)
template<int C>
__global__ __launch_bounds__(256) void dist_kernel(const float* __restrict__ x, const float* __restrict__ xx,
                                                   float* __restrict__ d, int b0) {
  constexpr int CC = (C < 64) ? C : 64;
  __shared__ __align__(16) float xi[CC][64];
  __shared__ __align__(16) float xj[CC][64];
  int bl = blockIdx.z, b = b0 + bl;
  int i0 = blockIdx.y * 64, j0 = blockIdx.x * 64;
  int t = threadIdx.x;
  int tj = t & 15, ti = t >> 4;
  float acc[4][4] = {};
  const float* xb = x + (size_t)b * C * NN;
  for (int c0 = 0; c0 < C; c0 += CC) {
    __syncthreads();
    for (int p = t; p < CC * 64; p += 256) {
      int cc = p >> 6, col = p & 63;
      xi[cc][col] = xb[(size_t)(c0 + cc) * NN + i0 + col];
      xj[cc][col] = xb[(size_t)(c0 + cc) * NN + j0 + col];
    }
    __syncthreads();
    #pragma unroll
    for (int cc = 0; cc < CC; ++cc) {
      float4 A  = *reinterpret_cast<const float4*>(&xi[cc][ti * 4]);
      float4 Bv = *reinterpret_cast<const float4*>(&xj[cc][tj * 4]);
      float av[4] = {A.x, A.y, A.z, A.w};
      float bv[4] = {Bv.x, Bv.y, Bv.z, Bv.w};
      #pragma unroll
      for (int a = 0; a < 4; ++a)
        #pragma unroll
        for (int q = 0; q < 4; ++q)
          acc[a][q] = fmaf(av[a], bv[q], acc[a][q]);
    }
  }
  #pragma unroll
  for (int a = 0; a < 4; ++a) {
    int i = i0 + ti * 4 + a;
    float xxi = xx[b * NN + i];
    float4 o;
    o.x = 2.f * acc[a][0] - xxi - xx[b * NN + j0 + tj * 4 + 0];
    o.y = 2.f * acc[a][1] - xxi - xx[b * NN + j0 + tj * 4 + 1];
    o.z = 2.f * acc[a][2] - xxi - xx[b * NN + j0 + tj * 4 + 2];
    o.w = 2.f * acc[a][3] - xxi - xx[b * NN + j0 + tj * 4 + 3];
    *reinterpret_cast<float4*>(&d[((size_t)bl * NN + i) * NN + j0 + tj * 4]) = o;
  }
}

// ---- top-20 extraction per row (lower-index tie-break, matches lax.top_k set)
__global__ __launch_bounds__(256) void topk_kernel(const float* __restrict__ d, int* __restrict__ idx, int b0) {
  __shared__ float sd[NN];
  __shared__ float swv[4];
  __shared__ int   swi[4];
  int bl = blockIdx.y, b = b0 + bl, i = blockIdx.x;
  const float* row = d + ((size_t)bl * NN + i) * NN;
  int t = threadIdx.x;
  for (int j = t; j < NN; j += 256) sd[j] = row[j];
  __syncthreads();
  int lane = t & 63, w = t >> 6;
  int* op = idx + ((size_t)b * NN + i) * KK;
  for (int r = 0; r < KK; ++r) {
    float bv = -3.4e38f; int bi = NN;
    for (int j = t; j < NN; j += 256) {
      float v = sd[j];
      if (v > bv) { bv = v; bi = j; }
    }
    #pragma unroll
    for (int s = 1; s < 64; s <<= 1) {
      float ov = __shfl_xor(bv, s);
      int   oi = __shfl_xor(bi, s);
      if (ov > bv || (ov == bv && oi < bi)) { bv = ov; bi = oi; }
    }
    if (lane == 0) { swv[w] = bv; swi[w] = bi; }
    __syncthreads();
    if (t == 0) {
      float fv = swv[0]; int fi = swi[0];
      for (int w2 = 1; w2 < 4; ++w2)
        if (swv[w2] > fv || (swv[w2] == fv && swi[w2] < fi)) { fv = swv[w2]; fi = swi[w2]; }
      op[r] = fi;
      sd[fi] = -3.4e38f;
    }
    __syncthreads();
  }
}

// ---- P_lo[b][o][n] = sum_{c<C} W[o][c] x[b][c][n];  P_hi uses W[o][C+c]
template<int C, int O>
__global__ __launch_bounds__(256) void pgemm_kernel(const float* __restrict__ x, const float* __restrict__ W,
                                                    float* __restrict__ Plo, float* __restrict__ Phi) {
  constexpr int CC = (C < 64) ? C : 64;
  __shared__ __align__(16) float xs[CC][64];
  __shared__ __align__(16) float wls[CC][68];
  __shared__ __align__(16) float whs[CC][68];
  int b = blockIdx.z;
  int o0 = blockIdx.y * 64, n0 = blockIdx.x * 64;
  int t = threadIdx.x;
  int tn = t & 15, to = t >> 4;
  float accl[4][4] = {}, acch[4][4] = {};
  const float* xb = x + (size_t)b * C * NN;
  for (int c0 = 0; c0 < C; c0 += CC) {
    __syncthreads();
    for (int p = t; p < CC * 64; p += 256) {
      int cc = p >> 6, col = p & 63;
      xs[cc][col] = xb[(size_t)(c0 + cc) * NN + n0 + col];
    }
    for (int p = t; p < 64 * CC; p += 256) {
      int ol = p / CC, cc = p % CC;
      wls[cc][ol] = W[(size_t)(o0 + ol) * (2 * C) + c0 + cc];
      whs[cc][ol] = W[(size_t)(o0 + ol) * (2 * C) + C + c0 + cc];
    }
    __syncthreads();
    #pragma unroll
    for (int cc = 0; cc < CC; ++cc) {
      float4 X  = *reinterpret_cast<const float4*>(&xs[cc][tn * 4]);
      float4 Wl = *reinterpret_cast<const float4*>(&wls[cc][to * 4]);
      float4 Wh = *reinterpret_cast<const float4*>(&whs[cc][to * 4]);
      float xv[4] = {X.x, X.y, X.z, X.w};
      float wl[4] = {Wl.x, Wl.y, Wl.z, Wl.w};
      float wh[4] = {Wh.x, Wh.y, Wh.z, Wh.w};
      #pragma unroll
      for (int a = 0; a < 4; ++a)
        #pragma unroll
        for (int q = 0; q < 4; ++q) {
          accl[a][q] = fmaf(wl[a], xv[q], accl[a][q]);
          acch[a][q] = fmaf(wh[a], xv[q], acch[a][q]);
        }
    }
  }
  #pragma unroll
  for (int a = 0; a < 4; ++a) {
    int o = o0 + to * 4 + a;
    size_t base = ((size_t)b * O + o) * NN + n0 + tn * 4;
    float4 vl = {accl[a][0], accl[a][1], accl[a][2], accl[a][3]};
    float4 vh = {acch[a][0], acch[a][1], acch[a][2], acch[a][3]};
    *reinterpret_cast<float4*>(&Plo[base]) = vl;
    *reinterpret_cast<float4*>(&Phi[base]) = vh;
  }
}

// ---- edge max: block = (b, n-tile 64, o-chunk 32). Stage Plo row in LDS,
//      gathers become LDS reads; register-prefetch next row to hide latency.
__global__ __launch_bounds__(256) void edgemax_kernel(const float* __restrict__ Plo, const float* __restrict__ Phi,
    const int* __restrict__ idx, const float* __restrict__ g, const float* __restrict__ bt,
    const float* __restrict__ m, const float* __restrict__ v,
    float* __restrict__ xout, int O) {
  __shared__ __align__(16) float srow[NN];
  __shared__ __align__(16) float sphi[64];
  __shared__ int   sidx[64 * KK];
  __shared__ float sinv[32], ssb[32];
  int b = blockIdx.z, n0 = blockIdx.y * 64, o0 = blockIdx.x * 32;
  int t = threadIdx.x;
  if (t < 32) {
    float inv = g[o0 + t] / sqrtf(v[o0 + t] + EPSV);
    sinv[t] = inv; ssb[t] = bt[o0 + t] - m[o0 + t] * inv;
  }
  for (int p = t; p < 64 * KK; p += 256) sidx[p] = idx[((size_t)b * NN + n0) * KK + p];
  // prefetch first row into registers
  float4 cur = *reinterpret_cast<const float4*>(&Plo[((size_t)b * O + o0) * NN + t * 4]);
  float4 curphi;
  if (t < 16) curphi = *reinterpret_cast<const float4*>(&Phi[((size_t)b * O + o0) * NN + n0 + t * 4]);
  __syncthreads();
  int n = t >> 2, kg = t & 3;
  int j0 = sidx[n * KK + kg * 5 + 0];
  int j1 = sidx[n * KK + kg * 5 + 1];
  int j2 = sidx[n * KK + kg * 5 + 2];
  int j3 = sidx[n * KK + kg * 5 + 3];
  int j4 = sidx[n * KK + kg * 5 + 4];
  for (int oo = 0; oo < 32; ++oo) {
    *reinterpret_cast<float4*>(&srow[t * 4]) = cur;
    if (t < 16) *reinterpret_cast<float4*>(&sphi[t * 4]) = curphi;
    if (oo < 31) {  // issue next-row loads; latency hides under compute below
      cur = *reinterpret_cast<const float4*>(&Plo[((size_t)b * O + o0 + oo + 1) * NN + t * 4]);
      if (t < 16) curphi = *reinterpret_cast<const float4*>(&Phi[((size_t)b * O + o0 + oo + 1) * NN + n0 + t * 4]);
    }
    __syncthreads();
    float mx = srow[j0];
    mx = fmaxf(mx, srow[j1]);
    mx = fmaxf(mx, srow[j2]);
    mx = fmaxf(mx, srow[j3]);
    mx = fmaxf(mx, srow[j4]);
    mx = fmaxf(mx, __shfl_xor(mx, 1));
    mx = fmaxf(mx, __shfl_xor(mx, 2));
    if (kg == 0) {
      float z = mx - srow[n0 + n] + sphi[n];
      xout[((size_t)b * O + o0 + oo) * NN + n0 + n] = fmaxf(fmaf(z, sinv[oo], ssb[oo]), 0.f);
    }
    __syncthreads();
  }
}

// ---- conv5 (512->1024) fused with global max over n. 128n x 64o tile,
//      4o x 8n per thread, conflict-free wave mapping.
__global__ __launch_bounds__(256) void conv5_kernel(const float* __restrict__ x1, const float* __restrict__ x2,
    const float* __restrict__ x3, const float* __restrict__ x4, const float* __restrict__ W5,
    unsigned* __restrict__ henc) {
  __shared__ __align__(16) float xs[32][128];
  __shared__ __align__(16) float ws[32][68];
  __shared__ unsigned smax[64];
  int b = blockIdx.z;
  int n0 = blockIdx.x * 128, o0 = blockIdx.y * 64;
  int t = threadIdx.x;
  int to = t & 15, tn = t >> 4;
  float acc[4][8] = {};
  for (int c0 = 0; c0 < 512; c0 += 32) {
    const float* srcbase; int cbase;
    if (c0 < 64)       { srcbase = x1 + (size_t)b * 64  * NN; cbase = c0; }
    else if (c0 < 128) { srcbase = x2 + (size_t)b * 64  * NN; cbase = c0 - 64; }
    else if (c0 < 256) { srcbase = x3 + (size_t)b * 128 * NN; cbase = c0 - 128; }
    else               { srcbase = x4 + (size_t)b * 256 * NN; cbase = c0 - 256; }
    __syncthreads();
    #pragma unroll
    for (int r = 0; r < 4; ++r) {
      int f = t + 256 * r;              // 1024 float4 = 32c x 128n
      int cc = f >> 5, col = (f & 31) * 4;
      *reinterpret_cast<float4*>(&xs[cc][col]) =
        *reinterpret_cast<const float4*>(&srcbase[(size_t)(cbase + cc) * NN + n0 + col]);
    }
    #pragma unroll
    for (int p = t; p < 2048; p += 256) {
      int ol = p >> 5, cc = p & 31;
      ws[cc][ol] = W5[(size_t)(o0 + ol) * 512 + c0 + cc];
    }
    __syncthreads();
    #pragma unroll 4
    for (int cc = 0; cc < 32; ++cc) {
      float4 w  = *reinterpret_cast<const float4*>(&ws[cc][to * 4]);   // 2-way, free
      float4 xa = *reinterpret_cast<const float4*>(&xs[cc][tn * 8]);   // broadcast
      float4 xb = *reinterpret_cast<const float4*>(&xs[cc][tn * 8 + 4]);
      float wv[4] = {w.x, w.y, w.z, w.w};
      float xv[8] = {xa.x, xa.y, xa.z, xa.w, xb.x, xb.y, xb.z, xb.w};
      #pragma unroll
      for (int a = 0; a < 4; ++a)
        #pragma unroll
        for (int q = 0; q < 8; ++q)
          acc[a][q] = fmaf(wv[a], xv[q], acc[a][q]);
    }
  }
  if (t < 64) smax[t] = 0u;
  __syncthreads();
  #pragma unroll
  for (int a = 0; a < 4; ++a) {
    float mx = acc[a][0];
    #pragma unroll
    for (int q = 1; q < 8; ++q) mx = fmaxf(mx, acc[a][q]);
    mx = fmaxf(mx, __shfl_xor(mx, 16));  // reduce over tn within wave
    mx = fmaxf(mx, __shfl_xor(mx, 32));
    if ((t & 48) == 0) atomicMax(&smax[to * 4 + a], fenc(mx));
  }
  __syncthreads();
  if (t < 64) atomicMax(&henc[b * 1024 + o0 + t], smax[t]);
}

// ---- FC1: 64 blocks (B x 8 chunks of 64 outputs), 4 lanes per output row
__global__ __launch_bounds__(256) void fc1_kernel(
    const unsigned* __restrict__ henc,
    const float* __restrict__ g5, const float* __restrict__ b5, const float* __restrict__ m5, const float* __restrict__ v5,
    const float* __restrict__ L1W,
    const float* __restrict__ g6, const float* __restrict__ b6, const float* __restrict__ m6, const float* __restrict__ v6,
    float* __restrict__ y1) {
  __shared__ float sh[1024];
  int b = blockIdx.y, t = threadIdx.x;
  int o0 = blockIdx.x * 64;
  for (int o = t; o < 1024; o += 256) {
    float f = fdec(henc[b * 1024 + o]);
    float inv = g5[o] / sqrtf(v5[o] + EPSV);
    sh[o] = fmaxf(fmaf(f, inv, b5[o] - m5[o] * inv), 0.f);
  }
  __syncthreads();
  int o = o0 + (t >> 2), part = t & 3;
  float acc = 0.f;
  const float4* w4 = reinterpret_cast<const float4*>(L1W + (size_t)o * 1024 + part * 256);
  const float4* h4 = reinterpret_cast<const float4*>(sh + part * 256);
  #pragma unroll 8
  for (int c = 0; c < 64; ++c) {
    float4 a = w4[c], q = h4[c];
    acc = fmaf(a.x, q.x, fmaf(a.y, q.y, fmaf(a.z, q.z, fmaf(a.w, q.w, acc))));
  }
  acc += __shfl_xor(acc, 1);
  acc += __shfl_xor(acc, 2);
  if (part == 0) {
    float inv = g6[o] / sqrtf(v6[o] + EPSV);
    y1[b * 512 + o] = fmaxf(fmaf(acc, inv, b6[o] - m6[o] * inv), 0.f);
  }
}

// ---- FC2+FC3: one block per batch element
__global__ __launch_bounds__(256) void fc2_kernel(
    const float* __restrict__ y1,
    const float* __restrict__ L2W, const float* __restrict__ L2b,
    const float* __restrict__ g7, const float* __restrict__ b7, const float* __restrict__ m7, const float* __restrict__ v7,
    const float* __restrict__ L3W, const float* __restrict__ L3b,
    float* __restrict__ out) {
  __shared__ float sy1[512];
  __shared__ float sy2[256];
  int b = blockIdx.x, t = threadIdx.x;
  for (int o = t; o < 512; o += 256) sy1[o] = y1[b * 512 + o];
  __syncthreads();
  {
    int o = t;
    float acc = L2b[o];
    const float4* w4 = reinterpret_cast<const float4*>(L2W + (size_t)o * 512);
    const float4* q4 = reinterpret_cast<const float4*>(sy1);
    for (int c = 0; c < 128; ++c) {
      float4 a = w4[c], q = q4[c];
      acc = fmaf(a.x, q.x, fmaf(a.y, q.y, fmaf(a.z, q.z, fmaf(a.w, q.w, acc))));
    }
    float inv = g7[o] / sqrtf(v7[o] + EPSV);
    sy2[o] = fmaxf(fmaf(acc, inv, b7[o] - m7[o] * inv), 0.f);
  }
  __syncthreads();
  if (t < 8) {
    float acc = L3b[t];
    const float4* w4 = reinterpret_cast<const float4*>(L3W + (size_t)t * 256);
    const float4* q4 = reinterpret_cast<const float4*>(sy2);
    for (int c = 0; c < 64; ++c) {
      float4 a = w4[c], q = q4[c];
      acc = fmaf(a.x, q.x, fmaf(a.y, q.y, fmaf(a.z, q.z, fmaf(a.w, q.w, acc))));
    }
    out[b * 8 + t] = acc;
  }
}

extern "C" void kernel_launch(void* const* d_in, const int* in_sizes, int n_in,
                              void* d_out, int out_size, void* d_ws, size_t ws_size,
                              hipStream_t stream) {
  (void)in_sizes; (void)n_in; (void)out_size;
  const float* x   = (const float*)d_in[0];
  const float* W1  = (const float*)d_in[1];
  const float* W2  = (const float*)d_in[2];
  const float* W3  = (const float*)d_in[3];
  const float* W4  = (const float*)d_in[4];
  const float* W5  = (const float*)d_in[5];
  const float* bnp[7][4];
  for (int i = 0; i < 7; ++i)
    for (int j = 0; j < 4; ++j)
      bnp[i][j] = (const float*)d_in[6 + i * 4 + j];
  const float* L1W = (const float*)d_in[34];
  const float* L2W = (const float*)d_in[35];
  const float* L2b = (const float*)d_in[36];
  const float* L3W = (const float*)d_in[37];
  const float* L3b = (const float*)d_in[38];
  float* out = (float*)d_out;

  char* wsb = (char*)d_ws;
  size_t off = 0;
  auto alloc = [&](size_t bytes) -> void* {
    void* p = wsb + off; off += (bytes + 255) & ~(size_t)255; return p;
  };
  int*      idx  = (int*)     alloc((size_t)BB * NN * KK * 4);
  float*    xx   = (float*)   alloc((size_t)BB * NN * 4);
  float*    x1   = (float*)   alloc((size_t)BB * 64  * NN * 4);
  float*    x2   = (float*)   alloc((size_t)BB * 64  * NN * 4);
  float*    x3   = (float*)   alloc((size_t)BB * 128 * NN * 4);
  float*    x4   = (float*)   alloc((size_t)BB * 256 * NN * 4);
  float*    Plo  = (float*)   alloc((size_t)BB * 256 * NN * 4);
  float*    Phi  = (float*)   alloc((size_t)BB * 256 * NN * 4);
  unsigned* henc = (unsigned*)alloc((size_t)BB * 1024 * 4);
  float*    y1   = (float*)   alloc((size_t)BB * 512 * 4);
  size_t left = (ws_size > off) ? (ws_size - off) : 0;
  int nb = 8;
  while (nb > 1 && (size_t)nb * NN * NN * 4 > left) nb >>= 1;
  float* dbuf = (float*)(wsb + off);

  dim3 thr(256);
  #define KNN_PHASE(CIN, XIN)                                                              \
    xx_kernel<CIN><<<dim3(32), thr, 0, stream>>>(XIN, xx);                                 \
    for (int b0 = 0; b0 < BB; b0 += nb) {                                                  \
      dist_kernel<CIN><<<dim3(16, 16, nb), thr, 0, stream>>>(XIN, xx, dbuf, b0);           \
      topk_kernel<<<dim3(NN, nb), thr, 0, stream>>>(dbuf, idx, b0);                        \
    }

  // ---- level 1: x (C=4) -> x1 (O=64)
  KNN_PHASE(4, x)
  pgemm_kernel<4, 64><<<dim3(16, 1, BB), thr, 0, stream>>>(x, W1, Plo, Phi);
  edgemax_kernel<<<dim3(2, 16, BB), thr, 0, stream>>>(Plo, Phi, idx,
      bnp[0][0], bnp[0][1], bnp[0][2], bnp[0][3], x1, 64);
  // ---- level 2: x1 (C=64) -> x2 (O=64)
  KNN_PHASE(64, x1)
  pgemm_kernel<64, 64><<<dim3(16, 1, BB), thr, 0, stream>>>(x1, W2, Plo, Phi);
  edgemax_kernel<<<dim3(2, 16, BB), thr, 0, stream>>>(Plo, Phi, idx,
      bnp[1][0], bnp[1][1], bnp[1][2], bnp[1][3], x2, 64);
  // ---- level 3: x2 (C=64) -> x3 (O=128)
  KNN_PHASE(64, x2)
  pgemm_kernel<64, 128><<<dim3(16, 2, BB), thr, 0, stream>>>(x2, W3, Plo, Phi);
  edgemax_kernel<<<dim3(4, 16, BB), thr, 0, stream>>>(Plo, Phi, idx,
      bnp[2][0], bnp[2][1], bnp[2][2], bnp[2][3], x3, 128);
  // ---- level 4: x3 (C=128) -> x4 (O=256)
  KNN_PHASE(128, x3)
  pgemm_kernel<128, 256><<<dim3(16, 4, BB), thr, 0, stream>>>(x3, W4, Plo, Phi);
  edgemax_kernel<<<dim3(8, 16, BB), thr, 0, stream>>>(Plo, Phi, idx,
      bnp[3][0], bnp[3][1], bnp[3][2], bnp[3][3], x4, 256);
  #undef KNN_PHASE

  // ---- conv5 + global max-pool
  hipMemsetAsync(henc, 0, (size_t)BB * 1024 * 4, stream);
  conv5_kernel<<<dim3(8, 16, BB), thr, 0, stream>>>(x1, x2, x3, x4, W5, henc);

  // ---- FC head
  fc1_kernel<<<dim3(8, BB), thr, 0, stream>>>(henc,
      bnp[4][0], bnp[4][1], bnp[4][2], bnp[4][3], L1W,
      bnp[5][0], bnp[5][1], bnp[5][2], bnp[5][3], y1);
  fc2_kernel<<<dim3(BB), thr, 0, stream>>>(y1,
      L2W, L2b, bnp[6][0], bnp[6][1], bnp[6][2], bnp[6][3], L3W, L3b, out);
}

// Round 3
// 602.986 us; speedup vs baseline: 1.7237x; 1.5052x over previous
//
#include <hip/hip_runtime.h>
#include <cstdint>

#define BB 8
#define NN 1024
#define KK 20
#define EPSV 1e-5f

__device__ __forceinline__ unsigned fenc(float f) {
  unsigned u = __float_as_uint(f);
  return (u & 0x80000000u) ? ~u : (u | 0x80000000u);
}
__device__ __forceinline__ float fdec(unsigned u) {
  u = (u & 0x80000000u) ? (u & 0x7FFFFFFFu) : ~u;
  return __uint_as_float(u);
}

// ---- per-point squared norm: xx[b*N+n] = sum_c x[b][c][n]^2
template<int C>
__global__ __launch_bounds__(256) void xx_kernel(const float* __restrict__ x, float* __restrict__ xx) {
  int p = blockIdx.x * 256 + threadIdx.x;
  if (p >= BB * NN) return;
  int b = p >> 10, n = p & (NN - 1);
  const float* xb = x + (size_t)b * C * NN + n;
  float s = 0.f;
  #pragma unroll
  for (int c = 0; c < C; ++c) { float t = xb[(size_t)c * NN]; s = fmaf(t, t, s); }
  xx[p] = s;
}

// ---- pairwise d[i][j] = 2<xi,xj> - xx_i - xx_j  (64x64 tiles; batches b0..b0+nb-1)
template<int C>
__global__ __launch_bounds__(256) void dist_kernel(const float* __restrict__ x, const float* __restrict__ xx,
                                                   float* __restrict__ d, int b0) {
  constexpr int CC = (C < 64) ? C : 64;
  __shared__ __align__(16) float xi[CC][64];
  __shared__ __align__(16) float xj[CC][64];
  int bl = blockIdx.z, b = b0 + bl;
  int i0 = blockIdx.y * 64, j0 = blockIdx.x * 64;
  int t = threadIdx.x;
  int tj = t & 15, ti = t >> 4;
  float acc[4][4] = {};
  const float* xb = x + (size_t)b * C * NN;
  for (int c0 = 0; c0 < C; c0 += CC) {
    __syncthreads();
    for (int p = t; p < CC * 64; p += 256) {
      int cc = p >> 6, col = p & 63;
      xi[cc][col] = xb[(size_t)(c0 + cc) * NN + i0 + col];
      xj[cc][col] = xb[(size_t)(c0 + cc) * NN + j0 + col];
    }
    __syncthreads();
    #pragma unroll
    for (int cc = 0; cc < CC; ++cc) {
      float4 A  = *reinterpret_cast<const float4*>(&xi[cc][ti * 4]);
      float4 Bv = *reinterpret_cast<const float4*>(&xj[cc][tj * 4]);
      float av[4] = {A.x, A.y, A.z, A.w};
      float bv[4] = {Bv.x, Bv.y, Bv.z, Bv.w};
      #pragma unroll
      for (int a = 0; a < 4; ++a)
        #pragma unroll
        for (int q = 0; q < 4; ++q)
          acc[a][q] = fmaf(av[a], bv[q], acc[a][q]);
    }
  }
  #pragma unroll
  for (int a = 0; a < 4; ++a) {
    int i = i0 + ti * 4 + a;
    float xxi = xx[b * NN + i];
    float4 o;
    o.x = 2.f * acc[a][0] - xxi - xx[b * NN + j0 + tj * 4 + 0];
    o.y = 2.f * acc[a][1] - xxi - xx[b * NN + j0 + tj * 4 + 1];
    o.z = 2.f * acc[a][2] - xxi - xx[b * NN + j0 + tj * 4 + 2];
    o.w = 2.f * acc[a][3] - xxi - xx[b * NN + j0 + tj * 4 + 3];
    *reinterpret_cast<float4*>(&d[((size_t)bl * NN + i) * NN + j0 + tj * 4]) = o;
  }
}

// ---- top-20 per row: one wave per row, no LDS, no barriers.
// key = (fenc(val) << 10) | (1023 - j)  -> bigger value wins, tie -> smaller j
// (matches lax.top_k tie-break). Lane owns 16 elems, sorts in regs, 20 rounds
// of wave-argmax over lane heads with register shift-down on the winner.
__global__ __launch_bounds__(256) void topk_kernel(const float* __restrict__ d, int* __restrict__ idx, int b0) {
  int t = threadIdx.x;
  int wave = t >> 6, lane = t & 63;
  int bl = blockIdx.y, b = b0 + bl;
  int i = blockIdx.x * 4 + wave;
  const float* row = d + ((size_t)bl * NN + i) * NN;

  unsigned long long s[16];
  #pragma unroll
  for (int p = 0; p < 4; ++p) {
    float4 v = *reinterpret_cast<const float4*>(&row[p * 256 + lane * 4]);
    int j = p * 256 + lane * 4;
    s[p * 4 + 0] = ((unsigned long long)fenc(v.x) << 10) | (unsigned)(1023 - (j + 0));
    s[p * 4 + 1] = ((unsigned long long)fenc(v.y) << 10) | (unsigned)(1023 - (j + 1));
    s[p * 4 + 2] = ((unsigned long long)fenc(v.z) << 10) | (unsigned)(1023 - (j + 2));
    s[p * 4 + 3] = ((unsigned long long)fenc(v.w) << 10) | (unsigned)(1023 - (j + 3));
  }

  // bitonic sort, descending (s[0] = lane max); fully static after unroll
  #pragma unroll
  for (int k = 2; k <= 16; k <<= 1) {
    #pragma unroll
    for (int jj = k >> 1; jj > 0; jj >>= 1) {
      #pragma unroll
      for (int e = 0; e < 16; ++e) {
        int l = e ^ jj;
        if (l > e) {
          bool up = ((e & k) == 0);
          unsigned long long a = s[e], c = s[l];
          bool sw = up ? (a < c) : (a > c);
          if (sw) { s[e] = c; s[l] = a; }
        }
      }
    }
  }

  unsigned long long head = s[0];
  int myout = 0;
  #pragma unroll
  for (int r = 0; r < KK; ++r) {
    unsigned long long k = head;
    int src = lane;
    #pragma unroll
    for (int st = 1; st < 64; st <<= 1) {
      unsigned long long ok = __shfl_xor(k, st);
      int os = __shfl_xor(src, st);
      if (ok > k) { k = ok; src = os; }
    }
    if (lane == r) myout = 1023 - (int)(k & 1023u);
    if (lane == src) {
      head = s[1];
      #pragma unroll
      for (int e = 1; e < 15; ++e) s[e] = s[e + 1];
      s[15] = 0ull;
    }
  }
  if (lane < KK) idx[((size_t)b * NN + i) * KK + lane] = myout;
}

// ---- P_lo[b][o][n] = sum_{c<C} W[o][c] x[b][c][n];  P_hi uses W[o][C+c]
template<int C, int O>
__global__ __launch_bounds__(256) void pgemm_kernel(const float* __restrict__ x, const float* __restrict__ W,
                                                    float* __restrict__ Plo, float* __restrict__ Phi) {
  constexpr int CC = (C < 64) ? C : 64;
  __shared__ __align__(16) float xs[CC][64];
  __shared__ __align__(16) float wls[CC][68];
  __shared__ __align__(16) float whs[CC][68];
  int b = blockIdx.z;
  int o0 = blockIdx.y * 64, n0 = blockIdx.x * 64;
  int t = threadIdx.x;
  int tn = t & 15, to = t >> 4;
  float accl[4][4] = {}, acch[4][4] = {};
  const float* xb = x + (size_t)b * C * NN;
  for (int c0 = 0; c0 < C; c0 += CC) {
    __syncthreads();
    for (int p = t; p < CC * 64; p += 256) {
      int cc = p >> 6, col = p & 63;
      xs[cc][col] = xb[(size_t)(c0 + cc) * NN + n0 + col];
    }
    for (int p = t; p < 64 * CC; p += 256) {
      int ol = p / CC, cc = p % CC;
      wls[cc][ol] = W[(size_t)(o0 + ol) * (2 * C) + c0 + cc];
      whs[cc][ol] = W[(size_t)(o0 + ol) * (2 * C) + C + c0 + cc];
    }
    __syncthreads();
    #pragma unroll
    for (int cc = 0; cc < CC; ++cc) {
      float4 X  = *reinterpret_cast<const float4*>(&xs[cc][tn * 4]);
      float4 Wl = *reinterpret_cast<const float4*>(&wls[cc][to * 4]);
      float4 Wh = *reinterpret_cast<const float4*>(&whs[cc][to * 4]);
      float xv[4] = {X.x, X.y, X.z, X.w};
      float wl[4] = {Wl.x, Wl.y, Wl.z, Wl.w};
      float wh[4] = {Wh.x, Wh.y, Wh.z, Wh.w};
      #pragma unroll
      for (int a = 0; a < 4; ++a)
        #pragma unroll
        for (int q = 0; q < 4; ++q) {
          accl[a][q] = fmaf(wl[a], xv[q], accl[a][q]);
          acch[a][q] = fmaf(wh[a], xv[q], acch[a][q]);
        }
    }
  }
  #pragma unroll
  for (int a = 0; a < 4; ++a) {
    int o = o0 + to * 4 + a;
    size_t base = ((size_t)b * O + o) * NN + n0 + tn * 4;
    float4 vl = {accl[a][0], accl[a][1], accl[a][2], accl[a][3]};
    float4 vh = {acch[a][0], acch[a][1], acch[a][2], acch[a][3]};
    *reinterpret_cast<float4*>(&Plo[base]) = vl;
    *reinterpret_cast<float4*>(&Phi[base]) = vh;
  }
}

// ---- edge max: block = (b, n-tile 64, o-chunk 32). Stage Plo row in LDS,
//      gathers become LDS reads; register-prefetch next row to hide latency.
__global__ __launch_bounds__(256) void edgemax_kernel(const float* __restrict__ Plo, const float* __restrict__ Phi,
    const int* __restrict__ idx, const float* __restrict__ g, const float* __restrict__ bt,
    const float* __restrict__ m, const float* __restrict__ v,
    float* __restrict__ xout, int O) {
  __shared__ __align__(16) float srow[NN];
  __shared__ __align__(16) float sphi[64];
  __shared__ int   sidx[64 * KK];
  __shared__ float sinv[32], ssb[32];
  int b = blockIdx.z, n0 = blockIdx.y * 64, o0 = blockIdx.x * 32;
  int t = threadIdx.x;
  if (t < 32) {
    float inv = g[o0 + t] / sqrtf(v[o0 + t] + EPSV);
    sinv[t] = inv; ssb[t] = bt[o0 + t] - m[o0 + t] * inv;
  }
  for (int p = t; p < 64 * KK; p += 256) sidx[p] = idx[((size_t)b * NN + n0) * KK + p];
  float4 cur = *reinterpret_cast<const float4*>(&Plo[((size_t)b * O + o0) * NN + t * 4]);
  float4 curphi;
  if (t < 16) curphi = *reinterpret_cast<const float4*>(&Phi[((size_t)b * O + o0) * NN + n0 + t * 4]);
  __syncthreads();
  int n = t >> 2, kg = t & 3;
  int j0 = sidx[n * KK + kg * 5 + 0];
  int j1 = sidx[n * KK + kg * 5 + 1];
  int j2 = sidx[n * KK + kg * 5 + 2];
  int j3 = sidx[n * KK + kg * 5 + 3];
  int j4 = sidx[n * KK + kg * 5 + 4];
  for (int oo = 0; oo < 32; ++oo) {
    *reinterpret_cast<float4*>(&srow[t * 4]) = cur;
    if (t < 16) *reinterpret_cast<float4*>(&sphi[t * 4]) = curphi;
    if (oo < 31) {
      cur = *reinterpret_cast<const float4*>(&Plo[((size_t)b * O + o0 + oo + 1) * NN + t * 4]);
      if (t < 16) curphi = *reinterpret_cast<const float4*>(&Phi[((size_t)b * O + o0 + oo + 1) * NN + n0 + t * 4]);
    }
    __syncthreads();
    float mx = srow[j0];
    mx = fmaxf(mx, srow[j1]);
    mx = fmaxf(mx, srow[j2]);
    mx = fmaxf(mx, srow[j3]);
    mx = fmaxf(mx, srow[j4]);
    mx = fmaxf(mx, __shfl_xor(mx, 1));
    mx = fmaxf(mx, __shfl_xor(mx, 2));
    if (kg == 0) {
      float z = mx - srow[n0 + n] + sphi[n];
      xout[((size_t)b * O + o0 + oo) * NN + n0 + n] = fmaxf(fmaf(z, sinv[oo], ssb[oo]), 0.f);
    }
    __syncthreads();
  }
}

// ---- conv5 (512->1024) fused with global max over n. 128n x 64o tile,
//      4o x 8n per thread, conflict-free wave mapping.
__global__ __launch_bounds__(256) void conv5_kernel(const float* __restrict__ x1, const float* __restrict__ x2,
    const float* __restrict__ x3, const float* __restrict__ x4, const float* __restrict__ W5,
    unsigned* __restrict__ henc) {
  __shared__ __align__(16) float xs[32][128];
  __shared__ __align__(16) float ws[32][68];
  __shared__ unsigned smax[64];
  int b = blockIdx.z;
  int n0 = blockIdx.x * 128, o0 = blockIdx.y * 64;
  int t = threadIdx.x;
  int to = t & 15, tn = t >> 4;
  float acc[4][8] = {};
  for (int c0 = 0; c0 < 512; c0 += 32) {
    const float* srcbase; int cbase;
    if (c0 < 64)       { srcbase = x1 + (size_t)b * 64  * NN; cbase = c0; }
    else if (c0 < 128) { srcbase = x2 + (size_t)b * 64  * NN; cbase = c0 - 64; }
    else if (c0 < 256) { srcbase = x3 + (size_t)b * 128 * NN; cbase = c0 - 128; }
    else               { srcbase = x4 + (size_t)b * 256 * NN; cbase = c0 - 256; }
    __syncthreads();
    #pragma unroll
    for (int r = 0; r < 4; ++r) {
      int f = t + 256 * r;
      int cc = f >> 5, col = (f & 31) * 4;
      *reinterpret_cast<float4*>(&xs[cc][col]) =
        *reinterpret_cast<const float4*>(&srcbase[(size_t)(cbase + cc) * NN + n0 + col]);
    }
    #pragma unroll
    for (int p = t; p < 2048; p += 256) {
      int ol = p >> 5, cc = p & 31;
      ws[cc][ol] = W5[(size_t)(o0 + ol) * 512 + c0 + cc];
    }
    __syncthreads();
    #pragma unroll 4
    for (int cc = 0; cc < 32; ++cc) {
      float4 w  = *reinterpret_cast<const float4*>(&ws[cc][to * 4]);
      float4 xa = *reinterpret_cast<const float4*>(&xs[cc][tn * 8]);
      float4 xb = *reinterpret_cast<const float4*>(&xs[cc][tn * 8 + 4]);
      float wv[4] = {w.x, w.y, w.z, w.w};
      float xv[8] = {xa.x, xa.y, xa.z, xa.w, xb.x, xb.y, xb.z, xb.w};
      #pragma unroll
      for (int a = 0; a < 4; ++a)
        #pragma unroll
        for (int q = 0; q < 8; ++q)
          acc[a][q] = fmaf(wv[a], xv[q], acc[a][q]);
    }
  }
  if (t < 64) smax[t] = 0u;
  __syncthreads();
  #pragma unroll
  for (int a = 0; a < 4; ++a) {
    float mx = acc[a][0];
    #pragma unroll
    for (int q = 1; q < 8; ++q) mx = fmaxf(mx, acc[a][q]);
    mx = fmaxf(mx, __shfl_xor(mx, 16));
    mx = fmaxf(mx, __shfl_xor(mx, 32));
    if ((t & 48) == 0) atomicMax(&smax[to * 4 + a], fenc(mx));
  }
  __syncthreads();
  if (t < 64) atomicMax(&henc[b * 1024 + o0 + t], smax[t]);
}

// ---- FC1: 64 blocks (B x 8 chunks of 64 outputs), 4 lanes per output row
__global__ __launch_bounds__(256) void fc1_kernel(
    const unsigned* __restrict__ henc,
    const float* __restrict__ g5, const float* __restrict__ b5, const float* __restrict__ m5, const float* __restrict__ v5,
    const float* __restrict__ L1W,
    const float* __restrict__ g6, const float* __restrict__ b6, const float* __restrict__ m6, const float* __restrict__ v6,
    float* __restrict__ y1) {
  __shared__ float sh[1024];
  int b = blockIdx.y, t = threadIdx.x;
  int o0 = blockIdx.x * 64;
  for (int o = t; o < 1024; o += 256) {
    float f = fdec(henc[b * 1024 + o]);
    float inv = g5[o] / sqrtf(v5[o] + EPSV);
    sh[o] = fmaxf(fmaf(f, inv, b5[o] - m5[o] * inv), 0.f);
  }
  __syncthreads();
  int o = o0 + (t >> 2), part = t & 3;
  float acc = 0.f;
  const float4* w4 = reinterpret_cast<const float4*>(L1W + (size_t)o * 1024 + part * 256);
  const float4* h4 = reinterpret_cast<const float4*>(sh + part * 256);
  #pragma unroll 8
  for (int c = 0; c < 64; ++c) {
    float4 a = w4[c], q = h4[c];
    acc = fmaf(a.x, q.x, fmaf(a.y, q.y, fmaf(a.z, q.z, fmaf(a.w, q.w, acc))));
  }
  acc += __shfl_xor(acc, 1);
  acc += __shfl_xor(acc, 2);
  if (part == 0) {
    float inv = g6[o] / sqrtf(v6[o] + EPSV);
    y1[b * 512 + o] = fmaxf(fmaf(acc, inv, b6[o] - m6[o] * inv), 0.f);
  }
}

// ---- FC2+FC3: one block per batch element
__global__ __launch_bounds__(256) void fc2_kernel(
    const float* __restrict__ y1,
    const float* __restrict__ L2W, const float* __restrict__ L2b,
    const float* __restrict__ g7, const float* __restrict__ b7, const float* __restrict__ m7, const float* __restrict__ v7,
    const float* __restrict__ L3W, const float* __restrict__ L3b,
    float* __restrict__ out) {
  __shared__ float sy1[512];
  __shared__ float sy2[256];
  int b = blockIdx.x, t = threadIdx.x;
  for (int o = t; o < 512; o += 256) sy1[o] = y1[b * 512 + o];
  __syncthreads();
  {
    int o = t;
    float acc = L2b[o];
    const float4* w4 = reinterpret_cast<const float4*>(L2W + (size_t)o * 512);
    const float4* q4 = reinterpret_cast<const float4*>(sy1);
    for (int c = 0; c < 128; ++c) {
      float4 a = w4[c], q = q4[c];
      acc = fmaf(a.x, q.x, fmaf(a.y, q.y, fmaf(a.z, q.z, fmaf(a.w, q.w, acc))));
    }
    float inv = g7[o] / sqrtf(v7[o] + EPSV);
    sy2[o] = fmaxf(fmaf(acc, inv, b7[o] - m7[o] * inv), 0.f);
  }
  __syncthreads();
  if (t < 8) {
    float acc = L3b[t];
    const float4* w4 = reinterpret_cast<const float4*>(L3W + (size_t)t * 256);
    const float4* q4 = reinterpret_cast<const float4*>(sy2);
    for (int c = 0; c < 64; ++c) {
      float4 a = w4[c], q = q4[c];
      acc = fmaf(a.x, q.x, fmaf(a.y, q.y, fmaf(a.z, q.z, fmaf(a.w, q.w, acc))));
    }
    out[b * 8 + t] = acc;
  }
}

extern "C" void kernel_launch(void* const* d_in, const int* in_sizes, int n_in,
                              void* d_out, int out_size, void* d_ws, size_t ws_size,
                              hipStream_t stream) {
  (void)in_sizes; (void)n_in; (void)out_size;
  const float* x   = (const float*)d_in[0];
  const float* W1  = (const float*)d_in[1];
  const float* W2  = (const float*)d_in[2];
  const float* W3  = (const float*)d_in[3];
  const float* W4  = (const float*)d_in[4];
  const float* W5  = (const float*)d_in[5];
  const float* bnp[7][4];
  for (int i = 0; i < 7; ++i)
    for (int j = 0; j < 4; ++j)
      bnp[i][j] = (const float*)d_in[6 + i * 4 + j];
  const float* L1W = (const float*)d_in[34];
  const float* L2W = (const float*)d_in[35];
  const float* L2b = (const float*)d_in[36];
  const float* L3W = (const float*)d_in[37];
  const float* L3b = (const float*)d_in[38];
  float* out = (float*)d_out;

  char* wsb = (char*)d_ws;
  size_t off = 0;
  auto alloc = [&](size_t bytes) -> void* {
    void* p = wsb + off; off += (bytes + 255) & ~(size_t)255; return p;
  };
  int*      idx  = (int*)     alloc((size_t)BB * NN * KK * 4);
  float*    xx   = (float*)   alloc((size_t)BB * NN * 4);
  float*    x1   = (float*)   alloc((size_t)BB * 64  * NN * 4);
  float*    x2   = (float*)   alloc((size_t)BB * 64  * NN * 4);
  float*    x3   = (float*)   alloc((size_t)BB * 128 * NN * 4);
  float*    x4   = (float*)   alloc((size_t)BB * 256 * NN * 4);
  float*    Plo  = (float*)   alloc((size_t)BB * 256 * NN * 4);
  float*    Phi  = (float*)   alloc((size_t)BB * 256 * NN * 4);
  unsigned* henc = (unsigned*)alloc((size_t)BB * 1024 * 4);
  float*    y1   = (float*)   alloc((size_t)BB * 512 * 4);
  size_t left = (ws_size > off) ? (ws_size - off) : 0;
  int nb = 8;
  while (nb > 1 && (size_t)nb * NN * NN * 4 > left) nb >>= 1;
  float* dbuf = (float*)(wsb + off);

  dim3 thr(256);
  #define KNN_PHASE(CIN, XIN)                                                              \
    xx_kernel<CIN><<<dim3(32), thr, 0, stream>>>(XIN, xx);                                 \
    for (int b0 = 0; b0 < BB; b0 += nb) {                                                  \
      dist_kernel<CIN><<<dim3(16, 16, nb), thr, 0, stream>>>(XIN, xx, dbuf, b0);           \
      topk_kernel<<<dim3(NN / 4, nb), thr, 0, stream>>>(dbuf, idx, b0);                    \
    }

  // ---- level 1: x (C=4) -> x1 (O=64)
  KNN_PHASE(4, x)
  pgemm_kernel<4, 64><<<dim3(16, 1, BB), thr, 0, stream>>>(x, W1, Plo, Phi);
  edgemax_kernel<<<dim3(2, 16, BB), thr, 0, stream>>>(Plo, Phi, idx,
      bnp[0][0], bnp[0][1], bnp[0][2], bnp[0][3], x1, 64);
  // ---- level 2: x1 (C=64) -> x2 (O=64)
  KNN_PHASE(64, x1)
  pgemm_kernel<64, 64><<<dim3(16, 1, BB), thr, 0, stream>>>(x1, W2, Plo, Phi);
  edgemax_kernel<<<dim3(2, 16, BB), thr, 0, stream>>>(Plo, Phi, idx,
      bnp[1][0], bnp[1][1], bnp[1][2], bnp[1][3], x2, 64);
  // ---- level 3: x2 (C=64) -> x3 (O=128)
  KNN_PHASE(64, x2)
  pgemm_kernel<64, 128><<<dim3(16, 2, BB), thr, 0, stream>>>(x2, W3, Plo, Phi);
  edgemax_kernel<<<dim3(4, 16, BB), thr, 0, stream>>>(Plo, Phi, idx,
      bnp[2][0], bnp[2][1], bnp[2][2], bnp[2][3], x3, 128);
  // ---- level 4: x3 (C=128) -> x4 (O=256)
  KNN_PHASE(128, x3)
  pgemm_kernel<128, 256><<<dim3(16, 4, BB), thr, 0, stream>>>(x3, W4, Plo, Phi);
  edgemax_kernel<<<dim3(8, 16, BB), thr, 0, stream>>>(Plo, Phi, idx,
      bnp[3][0], bnp[3][1], bnp[3][2], bnp[3][3], x4, 256);
  #undef KNN_PHASE

  // ---- conv5 + global max-pool
  hipMemsetAsync(henc, 0, (size_t)BB * 1024 * 4, stream);
  conv5_kernel<<<dim3(8, 16, BB), thr, 0, stream>>>(x1, x2, x3, x4, W5, henc);

  // ---- FC head
  fc1_kernel<<<dim3(8, BB), thr, 0, stream>>>(henc,
      bnp[4][0], bnp[4][1], bnp[4][2], bnp[4][3], L1W,
      bnp[5][0], bnp[5][1], bnp[5][2], bnp[5][3], y1);
  fc2_kernel<<<dim3(BB), thr, 0, stream>>>(y1,
      L2W, L2b, bnp[6][0], bnp[6][1], bnp[6][2], bnp[6][3], L3W, L3b, out);
}